// Round 23
// baseline (256.932 us; speedup 1.0000x reference)
//
#include <hip/hip_runtime.h>

typedef short bf16x8 __attribute__((ext_vector_type(8)));
typedef float f32x4  __attribute__((ext_vector_type(4)));

#define EPSF 1e-5f

// ---------------- workspace layout (float element offsets) ----------------
// RULE (empirical, r6/7/13/14 all-zero failures vs 19 passes): every kernel's total
// argument size must be <= 64 bytes; never reuse a kernel name with a changed signature.
// RULE (r19): register ping-pong weight prefetch spills under tight VGPR caps.
#define OFF_P0   0          // 4,915,200 (conv ping)
#define OFF_U    1048576    //   409,600 (in P0 tail)
#define OFF_V    1572864    //   409,600
#define OFF_P1   4915200    // 1,228,800 (conv pong)
#define OFF_SS   6144000    // 384: SA2/SA3/SA4 stats accumulators (96 each)
#define OFF_SACC 6144384    // 96: layer-1 (SA1) stats accumulators
#define OFF_Q    6144512    // 16,384
#define OFF_WP   6160896    // 196,608 float-slots: WP_hi + WP_lo bf16 frags
#define OFF_W1UV 6357504    // 13,312  (52 x 256)
#define OFF_W1Q  6370816    // 166,400 (650 x 256)
#define OFF_FW1T 6537216    // 65,536
#define OFF_FC2T 6602752    // 65,536
#define OFF_FC3T 6668288    // 32,768
#define OFF_XG   6701056    // 16,384
// end: 6,717,440 floats = 25.6 MiB

__device__ __forceinline__ unsigned short f2bf(float f) {
    union { float f; unsigned u; } cv; cv.f = f;
    const unsigned u = cv.u;
    return (unsigned short)((u + 0x7fffu + ((u >> 16) & 1u)) >> 16);  // RNE
}
__device__ __forceinline__ float bf2f(unsigned short h) {
    union { unsigned u; float f; } cv; cv.u = (unsigned)h << 16; return cv.f;
}

// ---------------- prep — EXACT round-21/22 (args 48 B) ----------------
__global__ __launch_bounds__(256) void k_prep(
    const float* __restrict__ gw1, const float* __restrict__ gw234,
    const float* __restrict__ fw1, const float* __restrict__ fc2w,
    const float* __restrict__ fc3w, float* __restrict__ ws)
{
    int idx = blockIdx.x * 256 + threadIdx.x;
    if (idx < 16384) { ws[OFF_XG + idx] = 0.f; return; }
    idx -= 16384;
    if (idx < 384) {   // SA1 (96 at OFF_SACC) + SA2/3/4 (288 at OFF_SS)
        if (idx < 96) ws[OFF_SACC + idx] = 0.f;
        else          ws[OFF_SS + (idx - 96)] = 0.f;
        return;
    }
    idx -= 384;
    if (idx < 49152) {
        const int isLo = idx >= 24576;
        const int f = isLo ? idx - 24576 : idx;
        const int lane = f & 63;
        const int nt = (f >> 6) & 15;
        const int kb = (f >> 10) & 7;
        const int l  = f >> 13;
        const int o = nt * 16 + (lane & 15);
        const int k = kb * 32 + (lane >> 4) * 8;
        const float* src = gw234 + ((size_t)l * 256 + o) * 256 + k;
        unsigned short* dst = (unsigned short*)(ws + OFF_WP) + (size_t)idx * 8;
        #pragma unroll
        for (int j = 0; j < 8; ++j) {
            const float x = src[j];
            const unsigned short hi = f2bf(x);
            dst[j] = isLo ? f2bf(x - bf2f(hi)) : hi;
        }
        return;
    }
    idx -= 49152;
    if (idx < 13312) {
        const int o = idx & 255, k = idx >> 8;
        ws[OFF_W1UV + idx] = gw1[(size_t)o * 702 + k];
        return;
    }
    idx -= 13312;
    if (idx < 166400) {
        const int o = idx & 255, k = idx >> 8;
        ws[OFF_W1Q + idx] = gw1[(size_t)o * 702 + 52 + k];
        return;
    }
    idx -= 166400;
    if (idx < 65536) { const int o = idx & 255, k = idx >> 8; ws[OFF_FW1T + idx] = fw1[o * 256 + k];  return; }
    idx -= 65536;
    if (idx < 65536) { const int o = idx & 255, k = idx >> 8; ws[OFF_FC2T + idx] = fc2w[o * 256 + k]; return; }
    idx -= 65536;
    if (idx < 32768) { const int o = idx & 127, k = idx >> 7; ws[OFF_FC3T + idx] = fc3w[o * 256 + k]; return; }
}

// ---------------- conv layer 1 — EXACT round-22 (args 48 B) ----------------
__global__ __launch_bounds__(256) void k_convF(
    const float* __restrict__ img, const float* __restrict__ img2,
    const float* __restrict__ w, const float* __restrict__ bias,
    float* __restrict__ out, float* __restrict__ sacc)
{
    __shared__ float lds[3*17*82 + 648];
    __shared__ float lstat[48];
    float* lin = lds;
    float* lw  = lds + 3*17*82;

    const int b  = blockIdx.x / 5;
    const int ty = blockIdx.x % 5;
    const int oy0 = ty * 8;
    const int t = threadIdx.x;

    for (int i = t; i < 648; i += 256) {
        const int co = i % 24, tap = (i / 24) % 9, ci = i / 216;
        lw[i] = w[(co*3 + ci)*9 + tap];
    }
    if (t >= 64 && t < 112) lstat[t - 64] = 0.f;

    const float* src = (b < 64 ? img : img2) + (size_t)(b & 63) * 3 * 6400;
    for (int i = t; i < 3*17*82; i += 256) {
        const int ci = i / (17*82);
        const int r  = i % (17*82);
        const int y  = r / 82, x = r % 82;
        const int gy = 2*oy0 - 1 + y, gx = x - 1;
        float v = 0.f;
        if (gy >= 0 && gy < 80 && gx >= 0 && gx < 80)
            v = src[ci*6400 + gy*80 + gx];
        lin[i] = v;
    }
    __syncthreads();

    if (t < 240) {                    // 24 co x 10 quad-cols
        const int co = t % 24;
        const int qi = t / 24;
        const int i4 = qi * 4;
        const float bco = bias[co];
        const float* wp = lw + co;
        float ssum = 0.f, ssq = 0.f;
        #pragma unroll 2
        for (int j = 0; j < 8; ++j) {
            float s0 = bco, s1 = bco, s2 = bco, s3 = bco;
            #pragma unroll
            for (int ci = 0; ci < 3; ++ci) {
                const int base = (ci*17 + 2*j)*82 + 2*i4;
                const float* wc = wp + ci * 216;
                #pragma unroll
                for (int kh = 0; kh < 3; ++kh) {
                    const float* lr = lin + base + kh*82;
                    const float2 a0 = *(const float2*)lr;
                    const float2 a1 = *(const float2*)(lr + 2);
                    const float2 a2 = *(const float2*)(lr + 4);
                    const float2 a3 = *(const float2*)(lr + 6);
                    const float  a8 = lr[8];
                    const float w0 = wc[(kh*3 + 0)*24];
                    const float w1 = wc[(kh*3 + 1)*24];
                    const float w2 = wc[(kh*3 + 2)*24];
                    s0 += a0.x*w0 + a0.y*w1 + a1.x*w2;
                    s1 += a1.x*w0 + a1.y*w1 + a2.x*w2;
                    s2 += a2.x*w0 + a2.y*w1 + a3.x*w2;
                    s3 += a3.x*w0 + a3.y*w1 + a8  *w2;
                }
            }
            const size_t o = (((size_t)b*24 + co)*40 + oy0 + j)*40 + i4;
            const float v0 = fmaxf(s0, 0.f), v1 = fmaxf(s1, 0.f);
            const float v2 = fmaxf(s2, 0.f), v3 = fmaxf(s3, 0.f);
            out[o]   = v0;  out[o+1] = v1;  out[o+2] = v2;  out[o+3] = v3;
            ssum += v0 + v1 + v2 + v3;
            ssq  += v0*v0 + v1*v1 + v2*v2 + v3*v3;
        }
        atomicAdd(&lstat[co],      ssum);
        atomicAdd(&lstat[24 + co], ssq);
    }
    __syncthreads();
    if (t < 48) {
        const int img_i = b >> 6, c = t % 24;
        const int dst = (t < 24) ? (img_i*24 + c) : (48 + img_i*24 + c);
        atomicAdd(&sacc[dst], lstat[t]);
    }
}

// ---------------- conv layers 2-4 body — EXACT round-21/22 ----------------
__device__ __forceinline__ void conv_bn_body(
    const float* __restrict__ in, const float* __restrict__ sacc_in,
    const float* __restrict__ g, const float* __restrict__ beta,
    const float* __restrict__ w, const float* __restrict__ bias,
    float* __restrict__ out, float* __restrict__ sacc_out,
    float* lds, float* lss,
    const int IH, const int IW, const int OH, const int OW,
    const int TH, const int ntyB, const int NTILES, const float Nin)
{
    const int NR = 2*TH + 1, CSTR = IW + 2;
    float* lin = lds;
    float* lw  = lds + 5040;

    const int b   = blockIdx.x / ntyB;
    const int tyB = (blockIdx.x % ntyB) * NTILES;
    const int t = threadIdx.x;
    const int img_i = b >> 6;

    if (t < 48) {
        const int c = t % 24;
        const float mean = sacc_in[img_i*24 + c] / Nin;
        const float var  = sacc_in[48 + img_i*24 + c] / Nin - mean*mean;
        const float scale = g[c] * rsqrtf(var + EPSF);
        lss[t] = (t < 24) ? scale : (beta[c] - mean*scale);
    }
    for (int i = t; i < 5184; i += 256) {
        const int co = i % 24, tap = (i / 24) % 9, ci = i / 216;
        lw[i] = w[(co*24 + ci)*9 + tap];
    }
    __syncthreads();

    float ssum = 0.f, ssq = 0.f;
    const int myco = t % 24;
    bool have = false;

    for (int tile = 0; tile < NTILES; ++tile) {
        const int oy0 = (tyB + tile) * TH;
        for (int i = t; i < 24 * NR * CSTR; i += 256) {
            const int ci = i / (NR * CSTR);
            const int r  = i % (NR * CSTR);
            const int y  = r / CSTR, x = r % CSTR;
            const int gy = 2*oy0 - 1 + y, gx = x - 1;
            float v = 0.f;
            if (gy >= 0 && gy < IH && gx >= 0 && gx < IW)
                v = in[(((size_t)b*24 + ci)*IH + gy)*IW + gx] * lss[ci] + lss[24 + ci];
            lin[i] = v;
        }
        __syncthreads();

        const int THe = (TH < OH - oy0) ? TH : (OH - oy0);
        const int QPR = (OW + 3) >> 2;
        const int NWI = THe * QPR * 24;
        if (t < NWI) {
            const int co = myco;
            const int q  = t / 24;
            const int i4 = (q % QPR) * 4;
            const int j  = q / QPR;
            const int n4 = (OW - i4 < 4) ? (OW - i4) : 4;
            float s0 = bias[co], s1 = s0, s2 = s0, s3 = s0;
            const float* wp = lw + co;
            for (int ci = 0; ci < 24; ++ci) {
                const int base = (ci*NR + 2*j)*CSTR + 2*i4;
                const float* wc = wp + ci * 216;
                #pragma unroll
                for (int kh = 0; kh < 3; ++kh) {
                    const float* lr = lin + base + kh*CSTR;
                    const float2 a0 = *(const float2*)lr;
                    const float2 a1 = *(const float2*)(lr + 2);
                    const float2 a2 = *(const float2*)(lr + 4);
                    const float2 a3 = *(const float2*)(lr + 6);
                    const float  a8 = lr[8];
                    const float w0 = wc[(kh*3 + 0)*24];
                    const float w1 = wc[(kh*3 + 1)*24];
                    const float w2 = wc[(kh*3 + 2)*24];
                    s0 += a0.x*w0 + a0.y*w1 + a1.x*w2;
                    s1 += a1.x*w0 + a1.y*w1 + a2.x*w2;
                    s2 += a2.x*w0 + a2.y*w1 + a3.x*w2;
                    s3 += a3.x*w0 + a3.y*w1 + a8  *w2;
                }
            }
            const size_t o = (((size_t)b*24 + co)*OH + oy0 + j)*OW + i4;
            const float v0 = fmaxf(s0, 0.f);
            out[o] = v0;  ssum += v0;  ssq += v0*v0;
            if (n4 > 1) { const float v1 = fmaxf(s1, 0.f); out[o+1] = v1; ssum += v1; ssq += v1*v1; }
            if (n4 > 2) { const float v2 = fmaxf(s2, 0.f); out[o+2] = v2; ssum += v2; ssq += v2*v2; }
            if (n4 > 3) { const float v3 = fmaxf(s3, 0.f); out[o+3] = v3; ssum += v3; ssq += v3*v3; }
            have = true;
        }
        __syncthreads();
    }

    if (t < 48) lin[t] = 0.f;
    __syncthreads();
    if (have) { atomicAdd(&lin[myco], ssum); atomicAdd(&lin[24 + myco], ssq); }
    __syncthreads();
    if (t < 48) {
        const int c = t % 24;
        const int dst = (t < 24) ? (img_i*24 + c) : (48 + img_i*24 + c);
        atomicAdd(&sacc_out[dst], lin[t]);
    }
}

__global__ __launch_bounds__(256) void k_cva2(
    const float* __restrict__ in, const float* __restrict__ sacc_in,
    const float* __restrict__ g, const float* __restrict__ beta,
    const float* __restrict__ w, const float* __restrict__ bias,
    float* __restrict__ out, float* __restrict__ sacc_out)
{
    __shared__ float lds[10224];
    __shared__ float lss[48];
    conv_bn_body(in, sacc_in, g, beta, w, bias, out, sacc_out, lds, lss,
                 40, 40, 20, 20, 2, 5, 2, 64.f * 1600.f);
}
__global__ __launch_bounds__(256) void k_cva3(
    const float* __restrict__ in, const float* __restrict__ sacc_in,
    const float* __restrict__ g, const float* __restrict__ beta,
    const float* __restrict__ w, const float* __restrict__ bias,
    float* __restrict__ out, float* __restrict__ sacc_out)
{
    __shared__ float lds[10224];
    __shared__ float lss[48];
    conv_bn_body(in, sacc_in, g, beta, w, bias, out, sacc_out, lds, lss,
                 20, 20, 10, 10, 3, 2, 2, 64.f * 400.f);
}
__global__ __launch_bounds__(256) void k_cva4(
    const float* __restrict__ in, const float* __restrict__ sacc_in,
    const float* __restrict__ g, const float* __restrict__ beta,
    const float* __restrict__ w, const float* __restrict__ bias,
    float* __restrict__ out, float* __restrict__ sacc_out)
{
    __shared__ float lds[10224];
    __shared__ float lss[48];
    conv_bn_body(in, sacc_in, g, beta, w, bias, out, sacc_out, lds, lss,
                 10, 10, 5, 5, 5, 1, 1, 64.f * 100.f);
}

// ---------------- fused U,V + Q — EXACT round-21/22 (args 64 B) ----------------
__global__ __launch_bounds__(256) void k_uvq3(
    const float* __restrict__ P1, const float* __restrict__ sacc4,
    const float* __restrict__ g4, const float* __restrict__ beta4,
    const float* __restrict__ w1uvT, const float* __restrict__ w1qT,
    const float* __restrict__ gb, float* __restrict__ ws)
{
    __shared__ float f[650];
    __shared__ float lss[96];
    float* Ub = ws + OFF_U;
    float* Vb = ws + OFF_V;
    float* Qb = ws + OFF_Q;
    const int t = threadIdx.x;
    if (t < 96) {
        const int img = t / 48, s = t % 48, c = s % 24;
        const float Nf = 64.f * 25.f;
        const float mean = sacc4[img*24 + c] / Nf;
        const float var  = sacc4[48 + img*24 + c] / Nf - mean*mean;
        const float scale = g4[c] * rsqrtf(var + EPSF);
        lss[t] = (s < 24) ? scale : (beta4[c] - mean*scale);
    }
    __syncthreads();
    if (blockIdx.x < 1600) {
        const int row = blockIdx.x;
        const int b = row / 25, cell = row % 25;
        if (t < 26) {
            float v;
            if (t < 24)      v = P1[((size_t)(b*24 + t))*25 + cell] * lss[t] + lss[24 + t];
            else if (t == 24) v = ((float)cell / 5.f - 2.f) * 0.5f;
            else              v = ((float)(cell % 5) - 2.f) * 0.5f;
            f[t] = v;
        }
        __syncthreads();
        float su = 0.f, sv = 0.f;
        #pragma unroll
        for (int k = 0; k < 26; ++k) {
            su += f[k] * w1uvT[k*256 + t];
            sv += f[k] * w1uvT[(26 + k)*256 + t];
        }
        Ub[(size_t)row*256 + t] = su;
        Vb[(size_t)row*256 + t] = sv;
    } else {
        const int b = blockIdx.x - 1600;
        for (int i = t; i < 650; i += 256) {
            const int cell = i / 26, ff = i % 26;
            float v;
            if (ff < 24)      v = P1[((size_t)((64 + b)*24 + ff))*25 + cell] * lss[48 + ff] + lss[72 + ff];
            else if (ff == 24) v = ((float)cell / 5.f - 2.f) * 0.5f;
            else               v = ((float)(cell % 5) - 2.f) * 0.5f;
            f[i] = v;
        }
        __syncthreads();
        float s = gb[t];
        #pragma unroll 10
        for (int k = 0; k < 650; ++k) s += f[k] * w1qT[k*256 + t];
        Qb[b*256 + t] = s;
    }
}

// ---------------- MFMA g-MLP (bf16x3) + sum pool — r22 body; launch_bounds (256,5) ----------------
// Round-23 change: (256,4) -> (256,5). LDS is 32 KB -> HW allows 5 blocks/CU (160/32);
// the old bound pinned 4. VGPR cap 512/5 = 102 >> current 64, so no spill expected
// (spill signature = WRITE_SIZE blowup, r19). 20 waves/CU of extra TLP against the
// per-kb L2 weight-load latency holding MfmaUtil at 33%. Body/math unchanged.
__global__ __launch_bounds__(256, 5) void k_gmlp(
    const float* __restrict__ U, const float* __restrict__ V, const float* __restrict__ Q,
    const unsigned short* __restrict__ WP, const float* __restrict__ gb, float* __restrict__ xg)
{
    __shared__ unsigned short hhi[8192];   // 32x256 bf16 = 16 KB
    __shared__ unsigned short hlo[8192];
    const int b    = blockIdx.x / 20;
    const int row0 = (blockIdx.x % 20) * 32;
    const int tid  = threadIdx.x;
    const int lane = tid & 63, w = tid >> 6;
    const int w4 = w * 4;

    {
        const int r0 = w * 8;
        const float2* Q2 = (const float2*)(Q + b*256);
        const float2 q0 = Q2[lane], q1 = Q2[64 + lane];
        for (int rr = 0; rr < 8; ++rr) {
            const int row = r0 + rr;
            int p = row0 + row; if (p > 624) p = 624;
            const float2* u2p = (const float2*)(U + ((size_t)(b*25 + p % 25)) * 256);
            const float2* v2p = (const float2*)(V + ((size_t)(b*25 + p / 25)) * 256);
            #pragma unroll
            for (int cc = 0; cc < 2; ++cc) {
                const int cp = cc*64 + lane;
                const float2 u2 = u2p[cp], v2 = v2p[cp];
                const float2 q2 = cc ? q1 : q0;
                const float x0 = fmaxf(u2.x + v2.x + q2.x, 0.f);
                const float x1 = fmaxf(u2.y + v2.y + q2.y, 0.f);
                const unsigned short h0 = f2bf(x0), h1 = f2bf(x1);
                const float l0 = x0 - bf2f(h0), l1 = x1 - bf2f(h1);
                const int byte = (row*512 + cp*4) ^ ((row & 7) << 4);
                *(unsigned*)((char*)hhi + byte) = (unsigned)h0 | ((unsigned)h1 << 16);
                *(unsigned*)((char*)hlo + byte) = (unsigned)f2bf(l0) | ((unsigned)f2bf(l1) << 16);
            }
        }
    }
    __syncthreads();

    const bf16x8* WPB = (const bf16x8*)WP;
    f32x4 acc[2][4];   // [rowset][n]
    #pragma unroll 1
    for (int l = 0; l < 3; ++l) {
        #pragma unroll
        for (int rs = 0; rs < 2; ++rs)
            #pragma unroll
            for (int n = 0; n < 4; ++n) acc[rs][n] = (f32x4)0.f;

        #pragma unroll 1
        for (int kb = 0; kb < 8; ++kb) {
            bf16x8 wh[4], wl[4];
            #pragma unroll
            for (int n = 0; n < 4; ++n) {
                const bf16x8* p = WPB + ((size_t)((l*8 + kb)*16 + w4 + n))*64 + lane;
                wh[n] = p[0]; wl[n] = p[24576];
            }
            bf16x8 ahi[2], alo[2];
            #pragma unroll
            for (int rs = 0; rs < 2; ++rs) {
                const int ar = rs*16 + (lane & 15);
                const int off = (ar*512 + kb*64 + (lane >> 4)*16) ^ ((ar & 7) << 4);
                ahi[rs] = *(const bf16x8*)((char*)hhi + off);
                alo[rs] = *(const bf16x8*)((char*)hlo + off);
            }
            #pragma unroll
            for (int n = 0; n < 4; ++n) {
                #pragma unroll
                for (int rs = 0; rs < 2; ++rs) {
                    acc[rs][n] = __builtin_amdgcn_mfma_f32_16x16x32_bf16(ahi[rs], wh[n], acc[rs][n], 0, 0, 0);
                    acc[rs][n] = __builtin_amdgcn_mfma_f32_16x16x32_bf16(ahi[rs], wl[n], acc[rs][n], 0, 0, 0);
                    acc[rs][n] = __builtin_amdgcn_mfma_f32_16x16x32_bf16(alo[rs], wh[n], acc[rs][n], 0, 0, 0);
                }
            }
        }
        __syncthreads();
        if (l < 2) {
            #pragma unroll
            for (int n = 0; n < 4; ++n) {
                const int col = (w4 + n)*16 + (lane & 15);
                const float bias = gb[(l+1)*256 + col];
                #pragma unroll
                for (int rs = 0; rs < 2; ++rs) {
                    #pragma unroll
                    for (int r = 0; r < 4; ++r) {
                        const int row = rs*16 + 4*(lane >> 4) + r;
                        const float v = fmaxf(acc[rs][n][r] + bias, 0.f);
                        const unsigned short hv = f2bf(v);
                        const float lv = v - bf2f(hv);
                        const int byte = (row*512 + col*2) ^ ((row & 7) << 4);
                        *(unsigned short*)((char*)hhi + byte) = hv;
                        *(unsigned short*)((char*)hlo + byte) = f2bf(lv);
                    }
                }
            }
            __syncthreads();
        } else {
            #pragma unroll
            for (int n = 0; n < 4; ++n) {
                const int col = (w4 + n)*16 + (lane & 15);
                const float bias = gb[3*256 + col];
                float s = 0.f;
                #pragma unroll
                for (int rs = 0; rs < 2; ++rs) {
                    #pragma unroll
                    for (int r = 0; r < 4; ++r) {
                        const int row = rs*16 + 4*(lane >> 4) + r;
                        if (row0 + row < 625) s += fmaxf(acc[rs][n][r] + bias, 0.f);
                    }
                }
                s += __shfl_xor(s, 16);
                s += __shfl_xor(s, 32);
                if (lane < 16) atomicAdd(&xg[b*256 + col], s);
            }
        }
    }
}

// ---------------- fused head — EXACT round-11..22 (args 64 B) ----------------
__global__ __launch_bounds__(256) void k_head(
    const float* __restrict__ XG, const float* __restrict__ fw1T, const float* __restrict__ fb1,
    const float* __restrict__ fc2T, const float* __restrict__ fc2b,
    const float* __restrict__ fc3T, const float* __restrict__ fc3b, float* __restrict__ out)
{
    __shared__ float xa[256], xb[256], ys[128];
    const int b = blockIdx.x, t = threadIdx.x;
    xa[t] = XG[b*256 + t];
    __syncthreads();
    float s = fb1[t];
    #pragma unroll 8
    for (int k = 0; k < 256; ++k) s += xa[k] * fw1T[k*256 + t];
    xb[t] = fmaxf(s, 0.f);
    __syncthreads();
    s = fc2b[t];
    #pragma unroll 8
    for (int k = 0; k < 256; ++k) s += xb[k] * fc2T[k*256 + t];
    xa[t] = fmaxf(s, 0.f);
    __syncthreads();
    if (t < 128) {
        s = fc3b[t];
        #pragma unroll 8
        for (int k = 0; k < 256; ++k) s += xa[k] * fc3T[k*128 + t];
        ys[t] = s;
    }
    __syncthreads();
    if (t < 16) {
        float m = ys[t*8];
        #pragma unroll
        for (int i = 1; i < 8; ++i) m = fmaxf(m, ys[t*8 + i]);
        float e[8], sum = 0.f;
        #pragma unroll
        for (int i = 0; i < 8; ++i) { e[i] = expf(ys[t*8 + i] - m); sum += e[i]; }
        const float inv = 1.f / sum;
        #pragma unroll
        for (int i = 0; i < 8; ++i) out[b*128 + t*8 + i] = fmaxf(e[i]*inv, 0.001f);
    }
}

extern "C" void kernel_launch(void* const* d_in, const int* in_sizes, int n_in,
                              void* d_out, int out_size, void* d_ws, size_t ws_size,
                              hipStream_t stream)
{
    const float* img   = (const float*)d_in[0];
    const float* img2  = (const float*)d_in[1];
    const float* cw1   = (const float*)d_in[2];
    const float* cw234 = (const float*)d_in[3];
    const float* cb    = (const float*)d_in[4];
    const float* bng   = (const float*)d_in[5];
    const float* bnb   = (const float*)d_in[6];
    const float* gw1   = (const float*)d_in[7];
    const float* gw234 = (const float*)d_in[8];
    const float* gb    = (const float*)d_in[9];
    const float* fw1   = (const float*)d_in[10];
    const float* fb1   = (const float*)d_in[11];
    const float* fc2w  = (const float*)d_in[12];
    const float* fc2b  = (const float*)d_in[13];
    const float* fc3w  = (const float*)d_in[14];
    const float* fc3b  = (const float*)d_in[15];

    float* ws = (float*)d_ws;
    float* P0 = ws + OFF_P0;  float* P1 = ws + OFF_P1;
    float* SA1 = ws + OFF_SACC;
    float* SA2 = ws + OFF_SS;
    float* SA3 = ws + OFF_SS + 96;
    float* SA4 = ws + OFF_SS + 192;
    float* Ub = ws + OFF_U;   float* Vb  = ws + OFF_V;   float* Qb = ws + OFF_Q;
    unsigned short* WP = (unsigned short*)(ws + OFF_WP);
    float* W1UV = ws + OFF_W1UV; float* W1Q = ws + OFF_W1Q;
    float* FW1T = ws + OFF_FW1T; float* FC2T = ws + OFF_FC2T; float* FC3T = ws + OFF_FC3T;
    float* XG = ws + OFF_XG;
    float* out = (float*)d_out;

    hipLaunchKernelGGL(k_prep, dim3(1600), dim3(256), 0, stream, gw1, gw234, fw1, fc2w, fc3w, ws);

    // conv1 (+fused stats -> SA1)
    hipLaunchKernelGGL(k_convF, dim3(640), dim3(256), 0, stream, img, img2, cw1, cb, P0, SA1);
    // conv2: BN(SA1) in prologue, stats -> SA2
    hipLaunchKernelGGL(k_cva2, dim3(640), dim3(256), 0, stream,
                       P0, SA1, bng, bnb, cw234, cb + 24, P1, SA2);
    // conv3: BN(SA2), stats -> SA3
    hipLaunchKernelGGL(k_cva3, dim3(256), dim3(256), 0, stream,
                       P1, SA2, bng + 24, bnb + 24, cw234 + 5184, cb + 48, P0, SA3);
    // conv4: BN(SA3), stats -> SA4
    hipLaunchKernelGGL(k_cva4, dim3(128), dim3(256), 0, stream,
                       P0, SA3, bng + 48, bnb + 48, cw234 + 10368, cb + 72, P1, SA4);

    // fused U/V + Q with in-kernel layer-4 BN (blocks 0-1599 = uv, 1600-1663 = q)
    hipLaunchKernelGGL(k_uvq3, dim3(1664), dim3(256), 0, stream,
                       P1, SA4, bng + 72, bnb + 72, W1UV, W1Q, gb, ws);

    hipLaunchKernelGGL(k_gmlp, dim3(1280), dim3(256), 0, stream, Ub, Vb, Qb, WP, gb, XG);

    hipLaunchKernelGGL(k_head, dim3(64), dim3(256), 0, stream,
                       XG, FW1T, fb1, FC2T, fc2b, FC3T, fc3b, out);
}

// Round 24
// 230.813 us; speedup vs baseline: 1.1132x; 1.1132x over previous
//
#include <hip/hip_runtime.h>

typedef short bf16x8 __attribute__((ext_vector_type(8)));
typedef float f32x4  __attribute__((ext_vector_type(4)));

#define EPSF 1e-5f

// ---------------- workspace layout (float element offsets) ----------------
// RULE (empirical, r6/7/13/14 all-zero failures vs 20 passes): every kernel's total
// argument size must be <= 64 bytes; never reuse a kernel name with a changed signature.
// RULE (r19, r23): k_gmlp register allocation spills under BOTH tighter bounds
// ((256,5): VGPR squeezed 64->48, 20 MB scratch) and register ping-pong prefetch.
// (256,4) @ 64 VGPR / 16 waves/CU is the measured local optimum.
#define OFF_P0   0          // 4,915,200 (conv ping)
#define OFF_U    1048576    //   409,600 (in P0 tail)
#define OFF_V    1572864    //   409,600
#define OFF_P1   4915200    // 1,228,800 (conv pong)
#define OFF_SS   6144000    // 384: SA2/SA3/SA4 stats accumulators (96 each)
#define OFF_SACC 6144384    // 96: layer-1 (SA1) stats accumulators
#define OFF_Q    6144512    // 16,384
#define OFF_WP   6160896    // 196,608 float-slots: WP_hi + WP_lo bf16 frags
#define OFF_W1UV 6357504    // 13,312  (52 x 256)
#define OFF_W1Q  6370816    // 166,400 (650 x 256)
#define OFF_FW1T 6537216    // 65,536
#define OFF_FC2T 6602752    // 65,536
#define OFF_FC3T 6668288    // 32,768
#define OFF_XG   6701056    // 16,384
// end: 6,717,440 floats = 25.6 MiB

__device__ __forceinline__ unsigned short f2bf(float f) {
    union { float f; unsigned u; } cv; cv.f = f;
    const unsigned u = cv.u;
    return (unsigned short)((u + 0x7fffu + ((u >> 16) & 1u)) >> 16);  // RNE
}
__device__ __forceinline__ float bf2f(unsigned short h) {
    union { unsigned u; float f; } cv; cv.u = (unsigned)h << 16; return cv.f;
}

// ---------------- prep — EXACT round-21/22 (args 48 B) ----------------
__global__ __launch_bounds__(256) void k_prep(
    const float* __restrict__ gw1, const float* __restrict__ gw234,
    const float* __restrict__ fw1, const float* __restrict__ fc2w,
    const float* __restrict__ fc3w, float* __restrict__ ws)
{
    int idx = blockIdx.x * 256 + threadIdx.x;
    if (idx < 16384) { ws[OFF_XG + idx] = 0.f; return; }
    idx -= 16384;
    if (idx < 384) {   // SA1 (96 at OFF_SACC) + SA2/3/4 (288 at OFF_SS)
        if (idx < 96) ws[OFF_SACC + idx] = 0.f;
        else          ws[OFF_SS + (idx - 96)] = 0.f;
        return;
    }
    idx -= 384;
    if (idx < 49152) {
        const int isLo = idx >= 24576;
        const int f = isLo ? idx - 24576 : idx;
        const int lane = f & 63;
        const int nt = (f >> 6) & 15;
        const int kb = (f >> 10) & 7;
        const int l  = f >> 13;
        const int o = nt * 16 + (lane & 15);
        const int k = kb * 32 + (lane >> 4) * 8;
        const float* src = gw234 + ((size_t)l * 256 + o) * 256 + k;
        unsigned short* dst = (unsigned short*)(ws + OFF_WP) + (size_t)idx * 8;
        #pragma unroll
        for (int j = 0; j < 8; ++j) {
            const float x = src[j];
            const unsigned short hi = f2bf(x);
            dst[j] = isLo ? f2bf(x - bf2f(hi)) : hi;
        }
        return;
    }
    idx -= 49152;
    if (idx < 13312) {
        const int o = idx & 255, k = idx >> 8;
        ws[OFF_W1UV + idx] = gw1[(size_t)o * 702 + k];
        return;
    }
    idx -= 13312;
    if (idx < 166400) {
        const int o = idx & 255, k = idx >> 8;
        ws[OFF_W1Q + idx] = gw1[(size_t)o * 702 + 52 + k];
        return;
    }
    idx -= 166400;
    if (idx < 65536) { const int o = idx & 255, k = idx >> 8; ws[OFF_FW1T + idx] = fw1[o * 256 + k];  return; }
    idx -= 65536;
    if (idx < 65536) { const int o = idx & 255, k = idx >> 8; ws[OFF_FC2T + idx] = fc2w[o * 256 + k]; return; }
    idx -= 65536;
    if (idx < 32768) { const int o = idx & 127, k = idx >> 7; ws[OFF_FC3T + idx] = fc3w[o * 256 + k]; return; }
}

// ---------------- conv layer 1 — EXACT round-22 (args 48 B) ----------------
__global__ __launch_bounds__(256) void k_convF(
    const float* __restrict__ img, const float* __restrict__ img2,
    const float* __restrict__ w, const float* __restrict__ bias,
    float* __restrict__ out, float* __restrict__ sacc)
{
    __shared__ float lds[3*17*82 + 648];
    __shared__ float lstat[48];
    float* lin = lds;
    float* lw  = lds + 3*17*82;

    const int b  = blockIdx.x / 5;
    const int ty = blockIdx.x % 5;
    const int oy0 = ty * 8;
    const int t = threadIdx.x;

    for (int i = t; i < 648; i += 256) {
        const int co = i % 24, tap = (i / 24) % 9, ci = i / 216;
        lw[i] = w[(co*3 + ci)*9 + tap];
    }
    if (t >= 64 && t < 112) lstat[t - 64] = 0.f;

    const float* src = (b < 64 ? img : img2) + (size_t)(b & 63) * 3 * 6400;
    for (int i = t; i < 3*17*82; i += 256) {
        const int ci = i / (17*82);
        const int r  = i % (17*82);
        const int y  = r / 82, x = r % 82;
        const int gy = 2*oy0 - 1 + y, gx = x - 1;
        float v = 0.f;
        if (gy >= 0 && gy < 80 && gx >= 0 && gx < 80)
            v = src[ci*6400 + gy*80 + gx];
        lin[i] = v;
    }
    __syncthreads();

    if (t < 240) {                    // 24 co x 10 quad-cols
        const int co = t % 24;
        const int qi = t / 24;
        const int i4 = qi * 4;
        const float bco = bias[co];
        const float* wp = lw + co;
        float ssum = 0.f, ssq = 0.f;
        #pragma unroll 2
        for (int j = 0; j < 8; ++j) {
            float s0 = bco, s1 = bco, s2 = bco, s3 = bco;
            #pragma unroll
            for (int ci = 0; ci < 3; ++ci) {
                const int base = (ci*17 + 2*j)*82 + 2*i4;
                const float* wc = wp + ci * 216;
                #pragma unroll
                for (int kh = 0; kh < 3; ++kh) {
                    const float* lr = lin + base + kh*82;
                    const float2 a0 = *(const float2*)lr;
                    const float2 a1 = *(const float2*)(lr + 2);
                    const float2 a2 = *(const float2*)(lr + 4);
                    const float2 a3 = *(const float2*)(lr + 6);
                    const float  a8 = lr[8];
                    const float w0 = wc[(kh*3 + 0)*24];
                    const float w1 = wc[(kh*3 + 1)*24];
                    const float w2 = wc[(kh*3 + 2)*24];
                    s0 += a0.x*w0 + a0.y*w1 + a1.x*w2;
                    s1 += a1.x*w0 + a1.y*w1 + a2.x*w2;
                    s2 += a2.x*w0 + a2.y*w1 + a3.x*w2;
                    s3 += a3.x*w0 + a3.y*w1 + a8  *w2;
                }
            }
            const size_t o = (((size_t)b*24 + co)*40 + oy0 + j)*40 + i4;
            const float v0 = fmaxf(s0, 0.f), v1 = fmaxf(s1, 0.f);
            const float v2 = fmaxf(s2, 0.f), v3 = fmaxf(s3, 0.f);
            out[o]   = v0;  out[o+1] = v1;  out[o+2] = v2;  out[o+3] = v3;
            ssum += v0 + v1 + v2 + v3;
            ssq  += v0*v0 + v1*v1 + v2*v2 + v3*v3;
        }
        atomicAdd(&lstat[co],      ssum);
        atomicAdd(&lstat[24 + co], ssq);
    }
    __syncthreads();
    if (t < 48) {
        const int img_i = b >> 6, c = t % 24;
        const int dst = (t < 24) ? (img_i*24 + c) : (48 + img_i*24 + c);
        atomicAdd(&sacc[dst], lstat[t]);
    }
}

// ---------------- conv layers 2-4 body — EXACT round-21/22 ----------------
__device__ __forceinline__ void conv_bn_body(
    const float* __restrict__ in, const float* __restrict__ sacc_in,
    const float* __restrict__ g, const float* __restrict__ beta,
    const float* __restrict__ w, const float* __restrict__ bias,
    float* __restrict__ out, float* __restrict__ sacc_out,
    float* lds, float* lss,
    const int IH, const int IW, const int OH, const int OW,
    const int TH, const int ntyB, const int NTILES, const float Nin)
{
    const int NR = 2*TH + 1, CSTR = IW + 2;
    float* lin = lds;
    float* lw  = lds + 5040;

    const int b   = blockIdx.x / ntyB;
    const int tyB = (blockIdx.x % ntyB) * NTILES;
    const int t = threadIdx.x;
    const int img_i = b >> 6;

    if (t < 48) {
        const int c = t % 24;
        const float mean = sacc_in[img_i*24 + c] / Nin;
        const float var  = sacc_in[48 + img_i*24 + c] / Nin - mean*mean;
        const float scale = g[c] * rsqrtf(var + EPSF);
        lss[t] = (t < 24) ? scale : (beta[c] - mean*scale);
    }
    for (int i = t; i < 5184; i += 256) {
        const int co = i % 24, tap = (i / 24) % 9, ci = i / 216;
        lw[i] = w[(co*24 + ci)*9 + tap];
    }
    __syncthreads();

    float ssum = 0.f, ssq = 0.f;
    const int myco = t % 24;
    bool have = false;

    for (int tile = 0; tile < NTILES; ++tile) {
        const int oy0 = (tyB + tile) * TH;
        for (int i = t; i < 24 * NR * CSTR; i += 256) {
            const int ci = i / (NR * CSTR);
            const int r  = i % (NR * CSTR);
            const int y  = r / CSTR, x = r % CSTR;
            const int gy = 2*oy0 - 1 + y, gx = x - 1;
            float v = 0.f;
            if (gy >= 0 && gy < IH && gx >= 0 && gx < IW)
                v = in[(((size_t)b*24 + ci)*IH + gy)*IW + gx] * lss[ci] + lss[24 + ci];
            lin[i] = v;
        }
        __syncthreads();

        const int THe = (TH < OH - oy0) ? TH : (OH - oy0);
        const int QPR = (OW + 3) >> 2;
        const int NWI = THe * QPR * 24;
        if (t < NWI) {
            const int co = myco;
            const int q  = t / 24;
            const int i4 = (q % QPR) * 4;
            const int j  = q / QPR;
            const int n4 = (OW - i4 < 4) ? (OW - i4) : 4;
            float s0 = bias[co], s1 = s0, s2 = s0, s3 = s0;
            const float* wp = lw + co;
            for (int ci = 0; ci < 24; ++ci) {
                const int base = (ci*NR + 2*j)*CSTR + 2*i4;
                const float* wc = wp + ci * 216;
                #pragma unroll
                for (int kh = 0; kh < 3; ++kh) {
                    const float* lr = lin + base + kh*CSTR;
                    const float2 a0 = *(const float2*)lr;
                    const float2 a1 = *(const float2*)(lr + 2);
                    const float2 a2 = *(const float2*)(lr + 4);
                    const float2 a3 = *(const float2*)(lr + 6);
                    const float  a8 = lr[8];
                    const float w0 = wc[(kh*3 + 0)*24];
                    const float w1 = wc[(kh*3 + 1)*24];
                    const float w2 = wc[(kh*3 + 2)*24];
                    s0 += a0.x*w0 + a0.y*w1 + a1.x*w2;
                    s1 += a1.x*w0 + a1.y*w1 + a2.x*w2;
                    s2 += a2.x*w0 + a2.y*w1 + a3.x*w2;
                    s3 += a3.x*w0 + a3.y*w1 + a8  *w2;
                }
            }
            const size_t o = (((size_t)b*24 + co)*OH + oy0 + j)*OW + i4;
            const float v0 = fmaxf(s0, 0.f);
            out[o] = v0;  ssum += v0;  ssq += v0*v0;
            if (n4 > 1) { const float v1 = fmaxf(s1, 0.f); out[o+1] = v1; ssum += v1; ssq += v1*v1; }
            if (n4 > 2) { const float v2 = fmaxf(s2, 0.f); out[o+2] = v2; ssum += v2; ssq += v2*v2; }
            if (n4 > 3) { const float v3 = fmaxf(s3, 0.f); out[o+3] = v3; ssum += v3; ssq += v3*v3; }
            have = true;
        }
        __syncthreads();
    }

    if (t < 48) lin[t] = 0.f;
    __syncthreads();
    if (have) { atomicAdd(&lin[myco], ssum); atomicAdd(&lin[24 + myco], ssq); }
    __syncthreads();
    if (t < 48) {
        const int c = t % 24;
        const int dst = (t < 24) ? (img_i*24 + c) : (48 + img_i*24 + c);
        atomicAdd(&sacc_out[dst], lin[t]);
    }
}

__global__ __launch_bounds__(256) void k_cva2(
    const float* __restrict__ in, const float* __restrict__ sacc_in,
    const float* __restrict__ g, const float* __restrict__ beta,
    const float* __restrict__ w, const float* __restrict__ bias,
    float* __restrict__ out, float* __restrict__ sacc_out)
{
    __shared__ float lds[10224];
    __shared__ float lss[48];
    conv_bn_body(in, sacc_in, g, beta, w, bias, out, sacc_out, lds, lss,
                 40, 40, 20, 20, 2, 5, 2, 64.f * 1600.f);
}
__global__ __launch_bounds__(256) void k_cva3(
    const float* __restrict__ in, const float* __restrict__ sacc_in,
    const float* __restrict__ g, const float* __restrict__ beta,
    const float* __restrict__ w, const float* __restrict__ bias,
    float* __restrict__ out, float* __restrict__ sacc_out)
{
    __shared__ float lds[10224];
    __shared__ float lss[48];
    conv_bn_body(in, sacc_in, g, beta, w, bias, out, sacc_out, lds, lss,
                 20, 20, 10, 10, 3, 2, 2, 64.f * 400.f);
}
__global__ __launch_bounds__(256) void k_cva4(
    const float* __restrict__ in, const float* __restrict__ sacc_in,
    const float* __restrict__ g, const float* __restrict__ beta,
    const float* __restrict__ w, const float* __restrict__ bias,
    float* __restrict__ out, float* __restrict__ sacc_out)
{
    __shared__ float lds[10224];
    __shared__ float lss[48];
    conv_bn_body(in, sacc_in, g, beta, w, bias, out, sacc_out, lds, lss,
                 10, 10, 5, 5, 5, 1, 1, 64.f * 100.f);
}

// ---------------- fused U,V + Q — EXACT round-21/22 (args 64 B) ----------------
__global__ __launch_bounds__(256) void k_uvq3(
    const float* __restrict__ P1, const float* __restrict__ sacc4,
    const float* __restrict__ g4, const float* __restrict__ beta4,
    const float* __restrict__ w1uvT, const float* __restrict__ w1qT,
    const float* __restrict__ gb, float* __restrict__ ws)
{
    __shared__ float f[650];
    __shared__ float lss[96];
    float* Ub = ws + OFF_U;
    float* Vb = ws + OFF_V;
    float* Qb = ws + OFF_Q;
    const int t = threadIdx.x;
    if (t < 96) {
        const int img = t / 48, s = t % 48, c = s % 24;
        const float Nf = 64.f * 25.f;
        const float mean = sacc4[img*24 + c] / Nf;
        const float var  = sacc4[48 + img*24 + c] / Nf - mean*mean;
        const float scale = g4[c] * rsqrtf(var + EPSF);
        lss[t] = (s < 24) ? scale : (beta4[c] - mean*scale);
    }
    __syncthreads();
    if (blockIdx.x < 1600) {
        const int row = blockIdx.x;
        const int b = row / 25, cell = row % 25;
        if (t < 26) {
            float v;
            if (t < 24)      v = P1[((size_t)(b*24 + t))*25 + cell] * lss[t] + lss[24 + t];
            else if (t == 24) v = ((float)cell / 5.f - 2.f) * 0.5f;
            else              v = ((float)(cell % 5) - 2.f) * 0.5f;
            f[t] = v;
        }
        __syncthreads();
        float su = 0.f, sv = 0.f;
        #pragma unroll
        for (int k = 0; k < 26; ++k) {
            su += f[k] * w1uvT[k*256 + t];
            sv += f[k] * w1uvT[(26 + k)*256 + t];
        }
        Ub[(size_t)row*256 + t] = su;
        Vb[(size_t)row*256 + t] = sv;
    } else {
        const int b = blockIdx.x - 1600;
        for (int i = t; i < 650; i += 256) {
            const int cell = i / 26, ff = i % 26;
            float v;
            if (ff < 24)      v = P1[((size_t)((64 + b)*24 + ff))*25 + cell] * lss[48 + ff] + lss[72 + ff];
            else if (ff == 24) v = ((float)cell / 5.f - 2.f) * 0.5f;
            else               v = ((float)(cell % 5) - 2.f) * 0.5f;
            f[i] = v;
        }
        __syncthreads();
        float s = gb[t];
        #pragma unroll 10
        for (int k = 0; k < 650; ++k) s += f[k] * w1qT[k*256 + t];
        Qb[b*256 + t] = s;
    }
}

// ---------------- MFMA g-MLP (bf16x3) + sum pool — EXACT round-22 (launch_bounds (256,4)) ----------------
__global__ __launch_bounds__(256, 4) void k_gmlp(
    const float* __restrict__ U, const float* __restrict__ V, const float* __restrict__ Q,
    const unsigned short* __restrict__ WP, const float* __restrict__ gb, float* __restrict__ xg)
{
    __shared__ unsigned short hhi[8192];   // 32x256 bf16 = 16 KB
    __shared__ unsigned short hlo[8192];
    const int b    = blockIdx.x / 20;
    const int row0 = (blockIdx.x % 20) * 32;
    const int tid  = threadIdx.x;
    const int lane = tid & 63, w = tid >> 6;
    const int w4 = w * 4;

    {
        const int r0 = w * 8;
        const float2* Q2 = (const float2*)(Q + b*256);
        const float2 q0 = Q2[lane], q1 = Q2[64 + lane];
        for (int rr = 0; rr < 8; ++rr) {
            const int row = r0 + rr;
            int p = row0 + row; if (p > 624) p = 624;
            const float2* u2p = (const float2*)(U + ((size_t)(b*25 + p % 25)) * 256);
            const float2* v2p = (const float2*)(V + ((size_t)(b*25 + p / 25)) * 256);
            #pragma unroll
            for (int cc = 0; cc < 2; ++cc) {
                const int cp = cc*64 + lane;
                const float2 u2 = u2p[cp], v2 = v2p[cp];
                const float2 q2 = cc ? q1 : q0;
                const float x0 = fmaxf(u2.x + v2.x + q2.x, 0.f);
                const float x1 = fmaxf(u2.y + v2.y + q2.y, 0.f);
                const unsigned short h0 = f2bf(x0), h1 = f2bf(x1);
                const float l0 = x0 - bf2f(h0), l1 = x1 - bf2f(h1);
                const int byte = (row*512 + cp*4) ^ ((row & 7) << 4);
                *(unsigned*)((char*)hhi + byte) = (unsigned)h0 | ((unsigned)h1 << 16);
                *(unsigned*)((char*)hlo + byte) = (unsigned)f2bf(l0) | ((unsigned)f2bf(l1) << 16);
            }
        }
    }
    __syncthreads();

    const bf16x8* WPB = (const bf16x8*)WP;
    f32x4 acc[2][4];   // [rowset][n]
    #pragma unroll 1
    for (int l = 0; l < 3; ++l) {
        #pragma unroll
        for (int rs = 0; rs < 2; ++rs)
            #pragma unroll
            for (int n = 0; n < 4; ++n) acc[rs][n] = (f32x4)0.f;

        #pragma unroll 1
        for (int kb = 0; kb < 8; ++kb) {
            bf16x8 wh[4], wl[4];
            #pragma unroll
            for (int n = 0; n < 4; ++n) {
                const bf16x8* p = WPB + ((size_t)((l*8 + kb)*16 + w4 + n))*64 + lane;
                wh[n] = p[0]; wl[n] = p[24576];
            }
            bf16x8 ahi[2], alo[2];
            #pragma unroll
            for (int rs = 0; rs < 2; ++rs) {
                const int ar = rs*16 + (lane & 15);
                const int off = (ar*512 + kb*64 + (lane >> 4)*16) ^ ((ar & 7) << 4);
                ahi[rs] = *(const bf16x8*)((char*)hhi + off);
                alo[rs] = *(const bf16x8*)((char*)hlo + off);
            }
            #pragma unroll
            for (int n = 0; n < 4; ++n) {
                #pragma unroll
                for (int rs = 0; rs < 2; ++rs) {
                    acc[rs][n] = __builtin_amdgcn_mfma_f32_16x16x32_bf16(ahi[rs], wh[n], acc[rs][n], 0, 0, 0);
                    acc[rs][n] = __builtin_amdgcn_mfma_f32_16x16x32_bf16(ahi[rs], wl[n], acc[rs][n], 0, 0, 0);
                    acc[rs][n] = __builtin_amdgcn_mfma_f32_16x16x32_bf16(alo[rs], wh[n], acc[rs][n], 0, 0, 0);
                }
            }
        }
        __syncthreads();
        if (l < 2) {
            #pragma unroll
            for (int n = 0; n < 4; ++n) {
                const int col = (w4 + n)*16 + (lane & 15);
                const float bias = gb[(l+1)*256 + col];
                #pragma unroll
                for (int rs = 0; rs < 2; ++rs) {
                    #pragma unroll
                    for (int r = 0; r < 4; ++r) {
                        const int row = rs*16 + 4*(lane >> 4) + r;
                        const float v = fmaxf(acc[rs][n][r] + bias, 0.f);
                        const unsigned short hv = f2bf(v);
                        const float lv = v - bf2f(hv);
                        const int byte = (row*512 + col*2) ^ ((row & 7) << 4);
                        *(unsigned short*)((char*)hhi + byte) = hv;
                        *(unsigned short*)((char*)hlo + byte) = f2bf(lv);
                    }
                }
            }
            __syncthreads();
        } else {
            #pragma unroll
            for (int n = 0; n < 4; ++n) {
                const int col = (w4 + n)*16 + (lane & 15);
                const float bias = gb[3*256 + col];
                float s = 0.f;
                #pragma unroll
                for (int rs = 0; rs < 2; ++rs) {
                    #pragma unroll
                    for (int r = 0; r < 4; ++r) {
                        const int row = rs*16 + 4*(lane >> 4) + r;
                        if (row0 + row < 625) s += fmaxf(acc[rs][n][r] + bias, 0.f);
                    }
                }
                s += __shfl_xor(s, 16);
                s += __shfl_xor(s, 32);
                if (lane < 16) atomicAdd(&xg[b*256 + col], s);
            }
        }
    }
}

// ---------------- fused head — EXACT round-11..22 (args 64 B) ----------------
__global__ __launch_bounds__(256) void k_head(
    const float* __restrict__ XG, const float* __restrict__ fw1T, const float* __restrict__ fb1,
    const float* __restrict__ fc2T, const float* __restrict__ fc2b,
    const float* __restrict__ fc3T, const float* __restrict__ fc3b, float* __restrict__ out)
{
    __shared__ float xa[256], xb[256], ys[128];
    const int b = blockIdx.x, t = threadIdx.x;
    xa[t] = XG[b*256 + t];
    __syncthreads();
    float s = fb1[t];
    #pragma unroll 8
    for (int k = 0; k < 256; ++k) s += xa[k] * fw1T[k*256 + t];
    xb[t] = fmaxf(s, 0.f);
    __syncthreads();
    s = fc2b[t];
    #pragma unroll 8
    for (int k = 0; k < 256; ++k) s += xb[k] * fc2T[k*256 + t];
    xa[t] = fmaxf(s, 0.f);
    __syncthreads();
    if (t < 128) {
        s = fc3b[t];
        #pragma unroll 8
        for (int k = 0; k < 256; ++k) s += xa[k] * fc3T[k*128 + t];
        ys[t] = s;
    }
    __syncthreads();
    if (t < 16) {
        float m = ys[t*8];
        #pragma unroll
        for (int i = 1; i < 8; ++i) m = fmaxf(m, ys[t*8 + i]);
        float e[8], sum = 0.f;
        #pragma unroll
        for (int i = 0; i < 8; ++i) { e[i] = expf(ys[t*8 + i] - m); sum += e[i]; }
        const float inv = 1.f / sum;
        #pragma unroll
        for (int i = 0; i < 8; ++i) out[b*128 + t*8 + i] = fmaxf(e[i]*inv, 0.001f);
    }
}

extern "C" void kernel_launch(void* const* d_in, const int* in_sizes, int n_in,
                              void* d_out, int out_size, void* d_ws, size_t ws_size,
                              hipStream_t stream)
{
    const float* img   = (const float*)d_in[0];
    const float* img2  = (const float*)d_in[1];
    const float* cw1   = (const float*)d_in[2];
    const float* cw234 = (const float*)d_in[3];
    const float* cb    = (const float*)d_in[4];
    const float* bng   = (const float*)d_in[5];
    const float* bnb   = (const float*)d_in[6];
    const float* gw1   = (const float*)d_in[7];
    const float* gw234 = (const float*)d_in[8];
    const float* gb    = (const float*)d_in[9];
    const float* fw1   = (const float*)d_in[10];
    const float* fb1   = (const float*)d_in[11];
    const float* fc2w  = (const float*)d_in[12];
    const float* fc2b  = (const float*)d_in[13];
    const float* fc3w  = (const float*)d_in[14];
    const float* fc3b  = (const float*)d_in[15];

    float* ws = (float*)d_ws;
    float* P0 = ws + OFF_P0;  float* P1 = ws + OFF_P1;
    float* SA1 = ws + OFF_SACC;
    float* SA2 = ws + OFF_SS;
    float* SA3 = ws + OFF_SS + 96;
    float* SA4 = ws + OFF_SS + 192;
    float* Ub = ws + OFF_U;   float* Vb  = ws + OFF_V;   float* Qb = ws + OFF_Q;
    unsigned short* WP = (unsigned short*)(ws + OFF_WP);
    float* W1UV = ws + OFF_W1UV; float* W1Q = ws + OFF_W1Q;
    float* FW1T = ws + OFF_FW1T; float* FC2T = ws + OFF_FC2T; float* FC3T = ws + OFF_FC3T;
    float* XG = ws + OFF_XG;
    float* out = (float*)d_out;

    hipLaunchKernelGGL(k_prep, dim3(1600), dim3(256), 0, stream, gw1, gw234, fw1, fc2w, fc3w, ws);

    // conv1 (+fused stats -> SA1)
    hipLaunchKernelGGL(k_convF, dim3(640), dim3(256), 0, stream, img, img2, cw1, cb, P0, SA1);
    // conv2: BN(SA1) in prologue, stats -> SA2
    hipLaunchKernelGGL(k_cva2, dim3(640), dim3(256), 0, stream,
                       P0, SA1, bng, bnb, cw234, cb + 24, P1, SA2);
    // conv3: BN(SA2), stats -> SA3
    hipLaunchKernelGGL(k_cva3, dim3(256), dim3(256), 0, stream,
                       P1, SA2, bng + 24, bnb + 24, cw234 + 5184, cb + 48, P0, SA3);
    // conv4: BN(SA3), stats -> SA4
    hipLaunchKernelGGL(k_cva4, dim3(128), dim3(256), 0, stream,
                       P0, SA3, bng + 48, bnb + 48, cw234 + 10368, cb + 72, P1, SA4);

    // fused U/V + Q with in-kernel layer-4 BN (blocks 0-1599 = uv, 1600-1663 = q)
    hipLaunchKernelGGL(k_uvq3, dim3(1664), dim3(256), 0, stream,
                       P1, SA4, bng + 72, bnb + 72, W1UV, W1Q, gb, ws);

    hipLaunchKernelGGL(k_gmlp, dim3(1280), dim3(256), 0, stream, Ub, Vb, Qb, WP, gb, XG);

    hipLaunchKernelGGL(k_head, dim3(64), dim3(256), 0, stream,
                       XG, FW1T, fb1, FC2T, fc2b, FC3T, fc3b, out);
}